// Round 4
// baseline (11492.113 us; speedup 1.0000x reference)
//
#include <hip/hip_runtime.h>
#include <math.h>

#define T_STEPS 64
#define A_DIM   16
#define SEQ     1024      // T*A
#define HE      256       // encoder hidden per direction
#define DH      512       // decoder hidden
#define GE      1024      // 4*HE
#define GD      2048      // 4*DH

typedef _Float16 h2_t __attribute__((ext_vector_type(2)));

__device__ __forceinline__ float sigf(float x) { return 1.f / (1.f + __expf(-x)); }
// tanh via exp2-based __expf; args bounded here (|x| < ~4) so no overflow path.
__device__ __forceinline__ float tanh_fast(float x) {
    float e = __expf(-2.f * x);
    return (1.f - e) / (1.f + e);
}

__device__ __forceinline__ float fdot2f(h2_t a, h2_t b, float c) {
#if defined(__has_builtin) && __has_builtin(__builtin_amdgcn_fdot2)
    return __builtin_amdgcn_fdot2(a, b, c, false);
#else
    return c + (float)a.x * (float)b.x + (float)a.y * (float)b.y;
#endif
}

__device__ __forceinline__ float poll_comm(const float* p) {
    float v;
    do {
        v = __hip_atomic_load(p, __ATOMIC_RELAXED, __HIP_MEMORY_SCOPE_AGENT);
    } while (v == 0.f);
    return v - 4.0f;
}

__device__ __forceinline__ void post_comm(float* p, float h) {
    __hip_atomic_store(p, h + 4.0f, __ATOMIC_RELAXED, __HIP_MEMORY_SCOPE_AGENT);
}

// ---------------------------------------------------------------------------
// Weight pre-conversion: f32 pairs -> packed f16x2 words. n = #pairs.
// ---------------------------------------------------------------------------
__global__ void k_cvt(const float* __restrict__ src, unsigned int* __restrict__ dst, int n)
{
    int i = blockIdx.x * 256 + threadIdx.x;
    if (i < n) {
        h2_t h; h.x = (_Float16)src[2 * i]; h.y = (_Float16)src[2 * i + 1];
        dst[i] = *(unsigned int*)&h;
    }
}

// ---------------------------------------------------------------------------
// Embedding / decoder-input assembly
// ---------------------------------------------------------------------------
__global__ void k_embed(const int* __restrict__ lattice, const int* __restrict__ inputs,
                        const int* __restrict__ gold, const int* __restrict__ sos,
                        const float* __restrict__ lat_emb, const float* __restrict__ in_emb,
                        float* __restrict__ x, float* __restrict__ decin)
{
    int idx = blockIdx.x * 256 + threadIdx.x;
    if (idx < SEQ * 256) {
        int row = idx >> 8, e = idx & 255;
        int f = e >> 6, eo = e & 63;
        int id = lattice[row * 4 + f];
        x[idx] = lat_emb[id * 64 + eo];
    } else {
        int k = idx - SEQ * 256;
        if (k < T_STEPS * 512) {
            int t = k >> 9, d = k & 511;
            float val;
            if (d < 256) {
                int f = d >> 6, eo = d & 63;
                int id = (t == 0) ? sos[f]
                                  : lattice[(((t - 1) * A_DIM) + gold[t - 1]) * 4 + f];
                val = lat_emb[id * 64 + eo];
            } else {
                val = in_emb[inputs[t] * 256 + (d - 256)];
            }
            decin[k] = val;
        }
    }
}

// ---------------------------------------------------------------------------
// Generic fp32 GEMM: C[m,n] = bias[n] + sum_k A[m*lda+k] * B[n*ldbn + k*ldbk]
// ---------------------------------------------------------------------------
__global__ __launch_bounds__(256) void k_gemm(
    const float* __restrict__ A, int lda, long sA,
    const float* __restrict__ B, int ldbn, int ldbk, long sB,
    const float* __restrict__ bias, int sBias,
    float* __restrict__ C, int ldc, long sC,
    int M, int N, int K)
{
    int b = blockIdx.z;
    A += b * sA; B += b * sB; C += b * sC;
    if (bias) bias += (long)b * sBias;
    int n0 = blockIdx.x * 64, m0 = blockIdx.y * 64;
    __shared__ float As[64][17];
    __shared__ float Bs[64][17];
    int tid = threadIdx.x;
    int tn = tid & 15, tm = tid >> 4;
    float acc[4][4] = {};
    int lk = tid & 15, lr = tid >> 4;
    for (int k0 = 0; k0 < K; k0 += 16) {
#pragma unroll
        for (int i = 0; i < 4; i++) {
            int row = lr + i * 16;
            int am = m0 + row;
            As[row][lk] = (am < M) ? A[(long)am * lda + k0 + lk] : 0.f;
            int bn = n0 + row;
            Bs[row][lk] = (bn < N) ? B[(long)bn * ldbn + (long)(k0 + lk) * ldbk] : 0.f;
        }
        __syncthreads();
#pragma unroll
        for (int k = 0; k < 16; k++) {
            float av[4], bv[4];
#pragma unroll
            for (int i = 0; i < 4; i++) av[i] = As[tm * 4 + i][k];
#pragma unroll
            for (int j = 0; j < 4; j++) bv[j] = Bs[tn * 4 + j][k];
#pragma unroll
            for (int i = 0; i < 4; i++)
#pragma unroll
                for (int j = 0; j < 4; j++) acc[i][j] += av[i] * bv[j];
        }
        __syncthreads();
    }
#pragma unroll
    for (int i = 0; i < 4; i++) {
        int m = m0 + tm * 4 + i;
        if (m >= M) continue;
#pragma unroll
        for (int j = 0; j < 4; j++) {
            int n = n0 + tn * 4 + j;
            if (n < N) C[(long)m * ldc + n] = acc[i][j] + (bias ? bias[n] : 0.f);
        }
    }
}

// ---------------------------------------------------------------------------
// Encoder biLSTM recurrence, one layer. ONE 1024-thread BLOCK PER DIRECTION:
// all sync is __syncthreads. Thread (kq=tid>>8, j=tid&255) holds 4 gate rows'
// f16 weights over K-quarter kq in VGPRs (128 h2 regs). Anti-sink: w2 and y
// are NOT __restrict__, so the in-loop y store may alias the weight loads —
// the compiler cannot legally re-load weights inside the loop (R2 failure),
// and with no pins it has no reason to spill (R3 failure). Budget is explicit
// via __launch_bounds__(1024,4): 2048/4 = 512 VGPRs >> ~200 needed.
// ---------------------------------------------------------------------------
__global__ __launch_bounds__(1024, 4) void k_rec_enc(
    const float* __restrict__ pre,   // [2][SEQ][GE]
    const unsigned int* w2,          // [2][1024][128] packed f16x2  (no restrict!)
    float* y,                        // [SEQ][512]                   (no restrict!)
    float* hfin,                     // [512] this layer's slot
    float* cfin)                     // [512]
{
    const int tid = threadIdx.x;
    const int dir = blockIdx.x;
    const bool fwd = (dir == 0);
    const int j  = tid & 255;
    const int kq = tid >> 8;         // 0..3 K-quarter
    const float* pre_d = pre + (long)dir * SEQ * GE;

    // weights: rows g*256+j (g = gate), K-range [kq*64, kq*64+64)
    h2_t w[4][32];
    {
        const float4* wp = (const float4*)w2;   // 1 float4 = 4 h2
#pragma unroll
        for (int g = 0; g < 4; g++) {
            long base = ((long)dir * 1024 + g * 256 + j) * 32 + kq * 8;
#pragma unroll
            for (int i = 0; i < 8; i++) {
                float4 v = wp[base + i];
                const h2_t* hv = (const h2_t*)&v;
                w[g][i * 4 + 0] = hv[0];
                w[g][i * 4 + 1] = hv[1];
                w[g][i * 4 + 2] = hv[2];
                w[g][i * 4 + 3] = hv[3];
            }
        }
    }

    __shared__ __align__(16) _Float16 hsArr[HE];
    __shared__ float part[16 * 256];             // [(g*4+kq)*256 + j]
    if (tid < 256) hsArr[tid] = (_Float16)0.f;

    float c = 0.f, h_cur = 0.f;
    float p0 = 0.f, p1 = 0.f, p2 = 0.f, p3 = 0.f;
    if (tid < 256) {
        long t0 = fwd ? 0 : SEQ - 1;
        p0 = pre_d[t0 * GE + 0 * 256 + j];
        p1 = pre_d[t0 * GE + 1 * 256 + j];
        p2 = pre_d[t0 * GE + 2 * 256 + j];
        p3 = pre_d[t0 * GE + 3 * 256 + j];
    }
    __syncthreads();

    for (int s = 0; s < SEQ; s++) {
        const int t = fwd ? s : SEQ - 1 - s;
        // my K-quarter of h: 8 float4 = 32 h2 (wave-broadcast LDS reads)
        float4 hb[8];
        const float4* hv4 = (const float4*)(hsArr + kq * 64);
#pragma unroll
        for (int i = 0; i < 8; i++) hb[i] = hv4[i];
        const h2_t* hh = (const h2_t*)hb;
        float a0 = 0, a1 = 0, a2 = 0, a3 = 0;
#pragma unroll
        for (int k = 0; k < 32; k++) {
            a0 = fdot2f(w[0][k], hh[k], a0);
            a1 = fdot2f(w[1][k], hh[k], a1);
            a2 = fdot2f(w[2][k], hh[k], a2);
            a3 = fdot2f(w[3][k], hh[k], a3);
        }
        part[(0 * 4 + kq) * 256 + j] = a0;
        part[(1 * 4 + kq) * 256 + j] = a1;
        part[(2 * 4 + kq) * 256 + j] = a2;
        part[(3 * 4 + kq) * 256 + j] = a3;
        __syncthreads();
        if (tid < 256) {
            float gi = p0 + ((part[ 0 * 256 + j] + part[ 1 * 256 + j]) +
                             (part[ 2 * 256 + j] + part[ 3 * 256 + j]));
            float gf = p1 + ((part[ 4 * 256 + j] + part[ 5 * 256 + j]) +
                             (part[ 6 * 256 + j] + part[ 7 * 256 + j]));
            float gg = p2 + ((part[ 8 * 256 + j] + part[ 9 * 256 + j]) +
                             (part[10 * 256 + j] + part[11 * 256 + j]));
            float go = p3 + ((part[12 * 256 + j] + part[13 * 256 + j]) +
                             (part[14 * 256 + j] + part[15 * 256 + j]));
            if (s + 1 < SEQ) {                   // prefetch next step's pre
                long tn = fwd ? t + 1 : t - 1;
                p0 = pre_d[tn * GE + 0 * 256 + j];
                p1 = pre_d[tn * GE + 1 * 256 + j];
                p2 = pre_d[tn * GE + 2 * 256 + j];
                p3 = pre_d[tn * GE + 3 * 256 + j];
            }
            c = sigf(gf) * c + sigf(gi) * tanh_fast(gg);
            h_cur = sigf(go) * tanh_fast(c);
            hsArr[j] = (_Float16)h_cur;
            y[(long)t * 512 + dir * 256 + j] = h_cur;
        }
        __syncthreads();
    }
    if (tid < 256) {
        hfin[dir * 256 + j] = h_cur;
        cfin[dir * 256 + j] = c;
    }
}

// ---------------------------------------------------------------------------
// Decoder LSTM recurrence, one layer — EXACT R2 version (proven). 16 blocks;
// block r owns h[r*32..+32). Row K=512 split across thread pairs.
// ---------------------------------------------------------------------------
__global__ __launch_bounds__(256, 1) void k_rec_dec(
    const float* __restrict__ pre,    // [64][GD]
    const float* __restrict__ Whh,    // [GD][DH] (layer-selected)
    const float* __restrict__ hinit,  // [512]
    const float* __restrict__ cinit,  // [512]
    float* __restrict__ hseq,         // [64][512]
    float* __restrict__ comm)         // [64][512], zeroed before launch
{
    const int tid = threadIdx.x, r = blockIdx.x;
    const int kh = tid >> 7, rem = tid & 127;
    const int q = rem >> 5, jj = rem & 31;
    const int row = q * DH + r * 32 + jj;
    const int k0 = kh * 256;

    h2_t w2[128];
    {
        const float4* wr = (const float4*)(Whh + (long)row * DH + k0);
#pragma unroll
        for (int i = 0; i < 64; i++) {
            float4 v = wr[i];
            w2[2 * i]     = h2_t{(_Float16)v.x, (_Float16)v.y};
            w2[2 * i + 1] = h2_t{(_Float16)v.z, (_Float16)v.w};
        }
    }

    __shared__ __align__(16) _Float16 hsArr[DH];
    __shared__ float part[256];
    __shared__ float gate[128];
    hsArr[tid] = (_Float16)hinit[tid];
    hsArr[tid + 256] = (_Float16)hinit[tid + 256];
    float c = (tid < 32) ? cinit[r * 32 + tid] : 0.f;
    float pre_cur = (tid < 128) ? pre[row] : 0.f;
    float h_cur = 0.f;
    __syncthreads();

    for (int s = 0; s < T_STEPS; s++) {
        float acc = 0.f;
        const float4* hv = (const float4*)(hsArr + k0);
#pragma unroll
        for (int kk = 0; kk < 32; kk++) {
            float4 blk = hv[kk];
            const h2_t* hp = (const h2_t*)&blk;
            acc = fdot2f(w2[4 * kk + 0], hp[0], acc);
            acc = fdot2f(w2[4 * kk + 1], hp[1], acc);
            acc = fdot2f(w2[4 * kk + 2], hp[2], acc);
            acc = fdot2f(w2[4 * kk + 3], hp[3], acc);
        }
        part[tid] = acc;
        __syncthreads();
        if (tid < 128) {
            float g = part[tid] + part[tid + 128] + pre_cur;
            if (s + 1 < T_STEPS) pre_cur = pre[(long)(s + 1) * GD + row];
            gate[tid] = g;
        }
        __syncthreads();
        if (tid < 32) {
            int jg = r * 32 + tid;
            float gi = gate[tid], gf = gate[32 + tid], gg = gate[64 + tid], go = gate[96 + tid];
            c = sigf(gf) * c + sigf(gi) * tanh_fast(gg);
            h_cur = sigf(go) * tanh_fast(c);
            post_comm(&comm[(long)s * DH + jg], h_cur);
            hseq[(long)s * DH + jg] = h_cur;
            hsArr[jg] = (_Float16)h_cur;
        }
        if (s + 1 < T_STEPS) {
            if (tid < 224) {                       // remote rel offsets 32..255
                int idx = (r * 32 + 32 + tid) & 511;
                hsArr[idx] = (_Float16)poll_comm(&comm[(long)s * DH + idx]);
            }
            {                                      // remote rel offsets 256..511
                int idx = (r * 32 + 256 + tid) & 511;
                hsArr[idx] = (_Float16)poll_comm(&comm[(long)s * DH + idx]);
            }
        }
        __syncthreads();
    }
}

// ---------------------------------------------------------------------------
// Attention readout
// ---------------------------------------------------------------------------
__global__ void k_attn(const float* __restrict__ encK, const float* __restrict__ qs,
                       const float* __restrict__ v, const int* __restrict__ alens,
                       float* __restrict__ out)
{
    int t = blockIdx.x;
    int tid = threadIdx.x;
    int wave = tid >> 6, lane = tid & 63;
    int len = alens[t];
    const float* qt = qs + t * 256;
    for (int a = wave; a < A_DIM; a += 4) {
        const float* ek = encK + (long)(t * A_DIM + a) * 256;
        float sum = 0.f;
#pragma unroll
        for (int e = 0; e < 4; e++) {
            int d = lane * 4 + e;
            sum += v[d] * tanhf(ek[d] + qt[d]);
        }
        for (int off = 32; off; off >>= 1) sum += __shfl_down(sum, off, 64);
        if (lane == 0) out[t * A_DIM + a] = (a < len) ? sum : -1e10f;
    }
}

// ---------------------------------------------------------------------------
extern "C" void kernel_launch(void* const* d_in, const int* in_sizes, int n_in,
                              void* d_out, int out_size, void* d_ws, size_t ws_size,
                              hipStream_t stream)
{
    (void)in_sizes; (void)n_in; (void)out_size; (void)ws_size;
    const int*   lattice = (const int*)d_in[0];
    const int*   alens   = (const int*)d_in[1];
    const int*   inputs  = (const int*)d_in[2];
    const int*   gold    = (const int*)d_in[4];
    const int*   sos     = (const int*)d_in[5];
    const float* lat_emb = (const float*)d_in[6];
    const float* in_emb  = (const float*)d_in[7];
    const float* Wih0    = (const float*)d_in[8];
    const float* Whh0    = (const float*)d_in[9];
    const float* b0      = (const float*)d_in[10];
    const float* Wih1    = (const float*)d_in[11];
    const float* Whh1    = (const float*)d_in[12];
    const float* b1      = (const float*)d_in[13];
    const float* dWih    = (const float*)d_in[14];
    const float* dWhh    = (const float*)d_in[15];
    const float* db      = (const float*)d_in[16];
    const float* Wq      = (const float*)d_in[17];
    const float* Wk      = (const float*)d_in[18];
    const float* av      = (const float*)d_in[19];
    float* out = (float*)d_out;
    float* ws  = (float*)d_ws;

    // ws layout (floats) — total 3,721,216 floats = 14.88 MB
    float* commD = ws;                  // 65536   [2 layers][64][512]
    unsigned int* wcvt = (unsigned int*)(ws + 65536); // 262144 words (one enc layer f16)
    float* xbuf  = ws + 327680;         // 262144
    float* pre   = ws + 589824;         // 2097152
    float* y0    = ws + 2686976;        // 524288  (layer outputs; L1 overwrites)
    float* hdec  = ws + 3211264;        // 1024    [2][512]
    float* cdec  = ws + 3212288;        // 1024
    float* decin = ws + 3213312;        // 32768   [64][512]
    float* encK  = ws + 3246080;        // 262144
    float* dpre  = ws + 3508224;        // 131072
    float* h0seq = ws + 3639296;        // 32768
    float* h1seq = ws + 3672064;        // 32768
    float* qseq  = ws + 3704832;        // 16384

    // zero decoder comm buffers (ws poisoned 0xAA before every launch)
    hipMemsetAsync(commD, 0, 65536 * sizeof(float), stream);

    k_embed<<<1152, 256, 0, stream>>>(lattice, inputs, gold, sos, lat_emb, in_emb, xbuf, decin);

    // pre = x @ Wih0^T + b0  (both dirs batched); convert Whh0 -> f16
    k_cvt<<<1024, 256, 0, stream>>>(Whh0, wcvt, 262144);
    k_gemm<<<dim3(16, 16, 2), 256, 0, stream>>>(
        xbuf, 256, 0L, Wih0, 256, 1, (long)GE * 256, b0, GE,
        pre, GE, (long)SEQ * GE, SEQ, GE, 256);
    k_rec_enc<<<2, 1024, 0, stream>>>(pre, wcvt, y0, hdec, cdec);

    // pre = y0 @ Wih1^T + b1; convert Whh1 -> f16
    k_cvt<<<1024, 256, 0, stream>>>(Whh1, wcvt, 262144);
    k_gemm<<<dim3(16, 16, 2), 256, 0, stream>>>(
        y0, 512, 0L, Wih1, 512, 1, (long)GE * 512, b1, GE,
        pre, GE, (long)SEQ * GE, SEQ, GE, 512);
    k_rec_enc<<<2, 1024, 0, stream>>>(pre, wcvt, y0, hdec + 512, cdec + 512);

    // encK = enc @ Wk
    k_gemm<<<dim3(4, 16, 1), 256, 0, stream>>>(
        y0, 512, 0L, Wk, 1, 256, 0L, nullptr, 0,
        encK, 256, 0L, SEQ, 256, 512);

    // dpre = decin @ dWih[0]^T + db[0]
    k_gemm<<<dim3(32, 1, 1), 256, 0, stream>>>(
        decin, 512, 0L, dWih, 512, 1, 0L, db, 0,
        dpre, GD, 0L, T_STEPS, GD, 512);
    k_rec_dec<<<16, 256, 0, stream>>>(dpre, dWhh, hdec, cdec, h0seq, commD);

    // dpre = h0seq @ dWih[1]^T + db[1]
    k_gemm<<<dim3(32, 1, 1), 256, 0, stream>>>(
        h0seq, 512, 0L, dWih + (long)GD * 512, 512, 1, 0L, db + GD, 0,
        dpre, GD, 0L, T_STEPS, GD, 512);
    k_rec_dec<<<16, 256, 0, stream>>>(dpre, dWhh + (long)GD * 512, hdec + 512, cdec + 512,
                                      h1seq, commD + 32768);

    // q = h1seq @ Wq
    k_gemm<<<dim3(4, 1, 1), 256, 0, stream>>>(
        h1seq, 512, 0L, Wq, 1, 256, 0L, nullptr, 0,
        qseq, 256, 0L, T_STEPS, 256, 512);

    k_attn<<<64, 256, 0, stream>>>(encK, qseq, av, alens, out);
}

// Round 6
// 8449.169 us; speedup vs baseline: 1.3601x; 1.3601x over previous
//
#include <hip/hip_runtime.h>
#include <math.h>

#define T_STEPS 64
#define A_DIM   16
#define SEQ     1024      // T*A
#define HE      256       // encoder hidden per direction
#define DH      512       // decoder hidden
#define GE      1024      // 4*HE
#define GD      2048      // 4*DH

typedef _Float16 h2_t __attribute__((ext_vector_type(2)));

__device__ __forceinline__ float sigf(float x) { return 1.f / (1.f + __expf(-x)); }
// tanh via exp2-based __expf; args bounded here (|x| < ~4) so no overflow path.
__device__ __forceinline__ float tanh_fast(float x) {
    float e = __expf(-2.f * x);
    return (1.f - e) / (1.f + e);
}

__device__ __forceinline__ float fdot2f(h2_t a, h2_t b, float c) {
#if defined(__has_builtin) && __has_builtin(__builtin_amdgcn_fdot2)
    return __builtin_amdgcn_fdot2(a, b, c, false);
#else
    return c + (float)a.x * (float)b.x + (float)a.y * (float)b.y;
#endif
}

__device__ __forceinline__ float dot2i(float acc, int w, int h) {
    union { int i; h2_t h; } uw, uh;
    uw.i = w; uh.i = h;
    return fdot2f(uw.h, uh.h, acc);
}

// ---- Volatile global loads: the anti-sink/anti-remat weight producer ------
// R2/R4: compiler sinks or re-loads weight loads inside the K-loop when it
// legally can. R3/R5: pins >256 arch VGPRs force spill; AGPRs can't feed
// VOP3P dot2. Fix: volatile asm load (cannot be re-executed or sunk) into
// plain VGPRs, total pressure kept < 256.
__device__ __forceinline__ int4 gld4i(const int4* p) {
    int4 r;
    asm volatile("global_load_dwordx4 %0, %1, off\n\ts_waitcnt vmcnt(0)"
                 : "=v"(r) : "v"(p) : "memory");
    return r;
}
__device__ __forceinline__ float4 gld4f(const float4* p) {
    float4 r;
    asm volatile("global_load_dwordx4 %0, %1, off\n\ts_waitcnt vmcnt(0)"
                 : "=v"(r) : "v"(p) : "memory");
    return r;
}

__device__ __forceinline__ float poll_comm(const float* p) {
    float v;
    do {
        v = __hip_atomic_load(p, __ATOMIC_RELAXED, __HIP_MEMORY_SCOPE_AGENT);
    } while (v == 0.f);
    return v - 4.0f;
}

__device__ __forceinline__ void post_comm(float* p, float h) {
    __hip_atomic_store(p, h + 4.0f, __ATOMIC_RELAXED, __HIP_MEMORY_SCOPE_AGENT);
}

// ---------------------------------------------------------------------------
// Weight pre-conversion: f32 pairs -> packed f16x2 words. n = #pairs.
// ---------------------------------------------------------------------------
__global__ void k_cvt(const float* __restrict__ src, unsigned int* __restrict__ dst, int n)
{
    int i = blockIdx.x * 256 + threadIdx.x;
    if (i < n) {
        h2_t h; h.x = (_Float16)src[2 * i]; h.y = (_Float16)src[2 * i + 1];
        dst[i] = *(unsigned int*)&h;
    }
}

// ---------------------------------------------------------------------------
// Embedding / decoder-input assembly
// ---------------------------------------------------------------------------
__global__ void k_embed(const int* __restrict__ lattice, const int* __restrict__ inputs,
                        const int* __restrict__ gold, const int* __restrict__ sos,
                        const float* __restrict__ lat_emb, const float* __restrict__ in_emb,
                        float* __restrict__ x, float* __restrict__ decin)
{
    int idx = blockIdx.x * 256 + threadIdx.x;
    if (idx < SEQ * 256) {
        int row = idx >> 8, e = idx & 255;
        int f = e >> 6, eo = e & 63;
        int id = lattice[row * 4 + f];
        x[idx] = lat_emb[id * 64 + eo];
    } else {
        int k = idx - SEQ * 256;
        if (k < T_STEPS * 512) {
            int t = k >> 9, d = k & 511;
            float val;
            if (d < 256) {
                int f = d >> 6, eo = d & 63;
                int id = (t == 0) ? sos[f]
                                  : lattice[(((t - 1) * A_DIM) + gold[t - 1]) * 4 + f];
                val = lat_emb[id * 64 + eo];
            } else {
                val = in_emb[inputs[t] * 256 + (d - 256)];
            }
            decin[k] = val;
        }
    }
}

// ---------------------------------------------------------------------------
// Generic fp32 GEMM: C[m,n] = bias[n] + sum_k A[m*lda+k] * B[n*ldbn + k*ldbk]
// ---------------------------------------------------------------------------
__global__ __launch_bounds__(256) void k_gemm(
    const float* __restrict__ A, int lda, long sA,
    const float* __restrict__ B, int ldbn, int ldbk, long sB,
    const float* __restrict__ bias, int sBias,
    float* __restrict__ C, int ldc, long sC,
    int M, int N, int K)
{
    int b = blockIdx.z;
    A += b * sA; B += b * sB; C += b * sC;
    if (bias) bias += (long)b * sBias;
    int n0 = blockIdx.x * 64, m0 = blockIdx.y * 64;
    __shared__ float As[64][17];
    __shared__ float Bs[64][17];
    int tid = threadIdx.x;
    int tn = tid & 15, tm = tid >> 4;
    float acc[4][4] = {};
    int lk = tid & 15, lr = tid >> 4;
    for (int k0 = 0; k0 < K; k0 += 16) {
#pragma unroll
        for (int i = 0; i < 4; i++) {
            int row = lr + i * 16;
            int am = m0 + row;
            As[row][lk] = (am < M) ? A[(long)am * lda + k0 + lk] : 0.f;
            int bn = n0 + row;
            Bs[row][lk] = (bn < N) ? B[(long)bn * ldbn + (long)(k0 + lk) * ldbk] : 0.f;
        }
        __syncthreads();
#pragma unroll
        for (int k = 0; k < 16; k++) {
            float av[4], bv[4];
#pragma unroll
            for (int i = 0; i < 4; i++) av[i] = As[tm * 4 + i][k];
#pragma unroll
            for (int j = 0; j < 4; j++) bv[j] = Bs[tn * 4 + j][k];
#pragma unroll
            for (int i = 0; i < 4; i++)
#pragma unroll
                for (int j = 0; j < 4; j++) acc[i][j] += av[i] * bv[j];
        }
        __syncthreads();
    }
#pragma unroll
    for (int i = 0; i < 4; i++) {
        int m = m0 + tm * 4 + i;
        if (m >= M) continue;
#pragma unroll
        for (int j = 0; j < 4; j++) {
            int n = n0 + tn * 4 + j;
            if (n < N) C[(long)m * ldc + n] = acc[i][j] + (bias ? bias[n] : 0.f);
        }
    }
}

// ---------------------------------------------------------------------------
// Encoder biLSTM recurrence, one layer. ONE 1024-thread BLOCK PER DIRECTION:
// all sync is __syncthreads. Thread (kq=tid>>8, j=tid&255) holds 4 gate rows'
// f16 weights over K-quarter kq in 128 plain VGPRs, produced by volatile
// global_load_dwordx4 (cannot sink/remat). Total pressure ~190 < 256 cap.
// ---------------------------------------------------------------------------
__global__ __launch_bounds__(1024, 4) void k_rec_enc(
    const float* __restrict__ pre,   // [2][SEQ][GE]
    const unsigned int* __restrict__ w2,  // [2][1024][128] packed f16x2
    float* __restrict__ y,           // [SEQ][512]
    float* __restrict__ hfin,        // [512] this layer's slot
    float* __restrict__ cfin)        // [512]
{
    const int tid = threadIdx.x;
    const int dir = blockIdx.x;
    const bool fwd = (dir == 0);
    const int j  = tid & 255;
    const int kq = tid >> 8;         // 0..3 K-quarter
    const float* pre_d = pre + (long)dir * SEQ * GE;

    // weights: rows g*256+j (g = gate), K-range [kq*64, kq*64+64)
    int4 wreg[4][8];
    {
        const int4* wp = (const int4*)w2;   // 1 int4 = 4 packed f16x2
#pragma unroll
        for (int g = 0; g < 4; g++) {
            long base = ((long)dir * 1024 + g * 256 + j) * 32 + kq * 8;
#pragma unroll
            for (int i = 0; i < 8; i++) wreg[g][i] = gld4i(wp + base + i);
        }
    }

    __shared__ __align__(16) _Float16 hsArr[HE];
    __shared__ float part[16 * 256];             // [(g*4+kq)*256 + j]
    if (tid < 256) hsArr[tid] = (_Float16)0.f;

    float c = 0.f, h_cur = 0.f;
    float p0 = 0.f, p1 = 0.f, p2 = 0.f, p3 = 0.f;
    if (tid < 256) {
        long t0 = fwd ? 0 : SEQ - 1;
        p0 = pre_d[t0 * GE + 0 * 256 + j];
        p1 = pre_d[t0 * GE + 1 * 256 + j];
        p2 = pre_d[t0 * GE + 2 * 256 + j];
        p3 = pre_d[t0 * GE + 3 * 256 + j];
    }
    __syncthreads();

    for (int s = 0; s < SEQ; s++) {
        const int t = fwd ? s : SEQ - 1 - s;
        // my K-quarter of h: 8 int4 = 32 packed pairs (broadcast LDS reads)
        int4 hb[8];
        const int4* hv4 = (const int4*)(hsArr + kq * 64);
#pragma unroll
        for (int i = 0; i < 8; i++) hb[i] = hv4[i];
        float a0 = 0, a1 = 0, a2 = 0, a3 = 0;
#pragma unroll
        for (int i = 0; i < 8; i++) {
            int4 h4 = hb[i];
            int4 w0 = wreg[0][i], w1 = wreg[1][i], w2v = wreg[2][i], w3 = wreg[3][i];
            a0 = dot2i(a0, w0.x, h4.x); a0 = dot2i(a0, w0.y, h4.y);
            a0 = dot2i(a0, w0.z, h4.z); a0 = dot2i(a0, w0.w, h4.w);
            a1 = dot2i(a1, w1.x, h4.x); a1 = dot2i(a1, w1.y, h4.y);
            a1 = dot2i(a1, w1.z, h4.z); a1 = dot2i(a1, w1.w, h4.w);
            a2 = dot2i(a2, w2v.x, h4.x); a2 = dot2i(a2, w2v.y, h4.y);
            a2 = dot2i(a2, w2v.z, h4.z); a2 = dot2i(a2, w2v.w, h4.w);
            a3 = dot2i(a3, w3.x, h4.x); a3 = dot2i(a3, w3.y, h4.y);
            a3 = dot2i(a3, w3.z, h4.z); a3 = dot2i(a3, w3.w, h4.w);
        }
        part[(0 * 4 + kq) * 256 + j] = a0;
        part[(1 * 4 + kq) * 256 + j] = a1;
        part[(2 * 4 + kq) * 256 + j] = a2;
        part[(3 * 4 + kq) * 256 + j] = a3;
        __syncthreads();
        if (tid < 256) {
            float gi = p0 + ((part[ 0 * 256 + j] + part[ 1 * 256 + j]) +
                             (part[ 2 * 256 + j] + part[ 3 * 256 + j]));
            float gf = p1 + ((part[ 4 * 256 + j] + part[ 5 * 256 + j]) +
                             (part[ 6 * 256 + j] + part[ 7 * 256 + j]));
            float gg = p2 + ((part[ 8 * 256 + j] + part[ 9 * 256 + j]) +
                             (part[10 * 256 + j] + part[11 * 256 + j]));
            float go = p3 + ((part[12 * 256 + j] + part[13 * 256 + j]) +
                             (part[14 * 256 + j] + part[15 * 256 + j]));
            if (s + 1 < SEQ) {                   // prefetch next step's pre
                long tn = fwd ? t + 1 : t - 1;
                p0 = pre_d[tn * GE + 0 * 256 + j];
                p1 = pre_d[tn * GE + 1 * 256 + j];
                p2 = pre_d[tn * GE + 2 * 256 + j];
                p3 = pre_d[tn * GE + 3 * 256 + j];
            }
            c = sigf(gf) * c + sigf(gi) * tanh_fast(gg);
            h_cur = sigf(go) * tanh_fast(c);
            hsArr[j] = (_Float16)h_cur;
            y[(long)t * 512 + dir * 256 + j] = h_cur;
        }
        __syncthreads();
    }
    if (tid < 256) {
        hfin[dir * 256 + j] = h_cur;
        cfin[dir * 256 + j] = c;
    }
}

// ---------------------------------------------------------------------------
// Decoder LSTM recurrence, one layer — R2 structure (proven), weights held
// in plain VGPRs via volatile loads + in-register f16 convert. 16 blocks;
// block r owns h[r*32..+32). K=512 split across thread pairs.
// ---------------------------------------------------------------------------
__global__ __launch_bounds__(256, 1) void k_rec_dec(
    const float* __restrict__ pre,    // [64][GD]
    const float* __restrict__ Whh,    // [GD][DH] (layer-selected)
    const float* __restrict__ hinit,  // [512]
    const float* __restrict__ cinit,  // [512]
    float* __restrict__ hseq,         // [64][512]
    float* __restrict__ comm)         // [64][512], zeroed before launch
{
    const int tid = threadIdx.x, r = blockIdx.x;
    const int kh = tid >> 7, rem = tid & 127;
    const int q = rem >> 5, jj = rem & 31;
    const int row = q * DH + r * 32 + jj;
    const int k0 = kh * 256;

    int w[128];
    {
        const float4* wr = (const float4*)(Whh + (long)row * DH + k0);
#pragma unroll
        for (int i = 0; i < 64; i++) {
            float4 v = gld4f(wr + i);
            h2_t h01; h01.x = (_Float16)v.x; h01.y = (_Float16)v.y;
            h2_t h23; h23.x = (_Float16)v.z; h23.y = (_Float16)v.w;
            union { h2_t h; int i; } u0, u1;
            u0.h = h01; u1.h = h23;
            w[2 * i]     = u0.i;
            w[2 * i + 1] = u1.i;
        }
    }

    __shared__ __align__(16) _Float16 hsArr[DH];
    __shared__ float part[256];
    __shared__ float gate[128];
    hsArr[tid] = (_Float16)hinit[tid];
    hsArr[tid + 256] = (_Float16)hinit[tid + 256];
    float c = (tid < 32) ? cinit[r * 32 + tid] : 0.f;
    float pre_cur = (tid < 128) ? pre[row] : 0.f;
    float h_cur = 0.f;
    __syncthreads();

    for (int s = 0; s < T_STEPS; s++) {
        float acc = 0.f;
        const int4* hv = (const int4*)(hsArr + k0);
#pragma unroll
        for (int kk = 0; kk < 32; kk++) {
            int4 blk = hv[kk];
            acc = dot2i(acc, w[4 * kk + 0], blk.x);
            acc = dot2i(acc, w[4 * kk + 1], blk.y);
            acc = dot2i(acc, w[4 * kk + 2], blk.z);
            acc = dot2i(acc, w[4 * kk + 3], blk.w);
        }
        part[tid] = acc;
        __syncthreads();
        if (tid < 128) {
            float g = part[tid] + part[tid + 128] + pre_cur;
            if (s + 1 < T_STEPS) pre_cur = pre[(long)(s + 1) * GD + row];
            gate[tid] = g;
        }
        __syncthreads();
        if (tid < 32) {
            int jg = r * 32 + tid;
            float gi = gate[tid], gf = gate[32 + tid], gg = gate[64 + tid], go = gate[96 + tid];
            c = sigf(gf) * c + sigf(gi) * tanh_fast(gg);
            h_cur = sigf(go) * tanh_fast(c);
            post_comm(&comm[(long)s * DH + jg], h_cur);
            hseq[(long)s * DH + jg] = h_cur;
            hsArr[jg] = (_Float16)h_cur;
        }
        if (s + 1 < T_STEPS) {
            if (tid < 224) {                       // remote rel offsets 32..255
                int idx = (r * 32 + 32 + tid) & 511;
                hsArr[idx] = (_Float16)poll_comm(&comm[(long)s * DH + idx]);
            }
            {                                      // remote rel offsets 256..511
                int idx = (r * 32 + 256 + tid) & 511;
                hsArr[idx] = (_Float16)poll_comm(&comm[(long)s * DH + idx]);
            }
        }
        __syncthreads();
    }
}

// ---------------------------------------------------------------------------
// Attention readout
// ---------------------------------------------------------------------------
__global__ void k_attn(const float* __restrict__ encK, const float* __restrict__ qs,
                       const float* __restrict__ v, const int* __restrict__ alens,
                       float* __restrict__ out)
{
    int t = blockIdx.x;
    int tid = threadIdx.x;
    int wave = tid >> 6, lane = tid & 63;
    int len = alens[t];
    const float* qt = qs + t * 256;
    for (int a = wave; a < A_DIM; a += 4) {
        const float* ek = encK + (long)(t * A_DIM + a) * 256;
        float sum = 0.f;
#pragma unroll
        for (int e = 0; e < 4; e++) {
            int d = lane * 4 + e;
            sum += v[d] * tanhf(ek[d] + qt[d]);
        }
        for (int off = 32; off; off >>= 1) sum += __shfl_down(sum, off, 64);
        if (lane == 0) out[t * A_DIM + a] = (a < len) ? sum : -1e10f;
    }
}

// ---------------------------------------------------------------------------
extern "C" void kernel_launch(void* const* d_in, const int* in_sizes, int n_in,
                              void* d_out, int out_size, void* d_ws, size_t ws_size,
                              hipStream_t stream)
{
    (void)in_sizes; (void)n_in; (void)out_size; (void)ws_size;
    const int*   lattice = (const int*)d_in[0];
    const int*   alens   = (const int*)d_in[1];
    const int*   inputs  = (const int*)d_in[2];
    const int*   gold    = (const int*)d_in[4];
    const int*   sos     = (const int*)d_in[5];
    const float* lat_emb = (const float*)d_in[6];
    const float* in_emb  = (const float*)d_in[7];
    const float* Wih0    = (const float*)d_in[8];
    const float* Whh0    = (const float*)d_in[9];
    const float* b0      = (const float*)d_in[10];
    const float* Wih1    = (const float*)d_in[11];
    const float* Whh1    = (const float*)d_in[12];
    const float* b1      = (const float*)d_in[13];
    const float* dWih    = (const float*)d_in[14];
    const float* dWhh    = (const float*)d_in[15];
    const float* db      = (const float*)d_in[16];
    const float* Wq      = (const float*)d_in[17];
    const float* Wk      = (const float*)d_in[18];
    const float* av      = (const float*)d_in[19];
    float* out = (float*)d_out;
    float* ws  = (float*)d_ws;

    // ws layout (floats) — total 3,721,216 floats = 14.88 MB
    float* commD = ws;                  // 65536   [2 layers][64][512]
    unsigned int* wcvt = (unsigned int*)(ws + 65536); // 262144 words (one enc layer f16)
    float* xbuf  = ws + 327680;         // 262144
    float* pre   = ws + 589824;         // 2097152
    float* y0    = ws + 2686976;        // 524288  (layer outputs; L1 overwrites)
    float* hdec  = ws + 3211264;        // 1024    [2][512]
    float* cdec  = ws + 3212288;        // 1024
    float* decin = ws + 3213312;        // 32768   [64][512]
    float* encK  = ws + 3246080;        // 262144
    float* dpre  = ws + 3508224;        // 131072
    float* h0seq = ws + 3639296;        // 32768
    float* h1seq = ws + 3672064;        // 32768
    float* qseq  = ws + 3704832;        // 16384

    // zero decoder comm buffers (ws poisoned 0xAA before every launch)
    hipMemsetAsync(commD, 0, 65536 * sizeof(float), stream);

    k_embed<<<1152, 256, 0, stream>>>(lattice, inputs, gold, sos, lat_emb, in_emb, xbuf, decin);

    // pre = x @ Wih0^T + b0  (both dirs batched); convert Whh0 -> f16
    k_cvt<<<1024, 256, 0, stream>>>(Whh0, wcvt, 262144);
    k_gemm<<<dim3(16, 16, 2), 256, 0, stream>>>(
        xbuf, 256, 0L, Wih0, 256, 1, (long)GE * 256, b0, GE,
        pre, GE, (long)SEQ * GE, SEQ, GE, 256);
    k_rec_enc<<<2, 1024, 0, stream>>>(pre, wcvt, y0, hdec, cdec);

    // pre = y0 @ Wih1^T + b1; convert Whh1 -> f16
    k_cvt<<<1024, 256, 0, stream>>>(Whh1, wcvt, 262144);
    k_gemm<<<dim3(16, 16, 2), 256, 0, stream>>>(
        y0, 512, 0L, Wih1, 512, 1, (long)GE * 512, b1, GE,
        pre, GE, (long)SEQ * GE, SEQ, GE, 512);
    k_rec_enc<<<2, 1024, 0, stream>>>(pre, wcvt, y0, hdec + 512, cdec + 512);

    // encK = enc @ Wk
    k_gemm<<<dim3(4, 16, 1), 256, 0, stream>>>(
        y0, 512, 0L, Wk, 1, 256, 0L, nullptr, 0,
        encK, 256, 0L, SEQ, 256, 512);

    // dpre = decin @ dWih[0]^T + db[0]
    k_gemm<<<dim3(32, 1, 1), 256, 0, stream>>>(
        decin, 512, 0L, dWih, 512, 1, 0L, db, 0,
        dpre, GD, 0L, T_STEPS, GD, 512);
    k_rec_dec<<<16, 256, 0, stream>>>(dpre, dWhh, hdec, cdec, h0seq, commD);

    // dpre = h0seq @ dWih[1]^T + db[1]
    k_gemm<<<dim3(32, 1, 1), 256, 0, stream>>>(
        h0seq, 512, 0L, dWih + (long)GD * 512, 512, 1, 0L, db + GD, 0,
        dpre, GD, 0L, T_STEPS, GD, 512);
    k_rec_dec<<<16, 256, 0, stream>>>(dpre, dWhh + (long)GD * 512, hdec + 512, cdec + 512,
                                      h1seq, commD + 32768);

    // q = h1seq @ Wq
    k_gemm<<<dim3(4, 1, 1), 256, 0, stream>>>(
        h1seq, 512, 0L, Wq, 1, 256, 0L, nullptr, 0,
        qseq, 256, 0L, T_STEPS, 256, 512);

    k_attn<<<64, 256, 0, stream>>>(encK, qseq, av, alens, out);
}